// Round 8
// baseline (504.182 us; speedup 1.0000x reference)
//
#include <hip/hip_runtime.h>

// FillSimNet: 4-layer GCN forward.
// CSR build, fully atomic-free at global scope (deterministic 2-phase bucketing):
//   1. k_hist:    512 blocks x 3125 edges: LDS histogram by dst>>8 -> hist[b][j]
//   2. k_colscan: per-bucket scan over the 512 block counts -> off[b][j], totals[j]
//   3. k_bscan:   scan totals -> bucket_base[], row_ptr[NN]=NE
//   4. k_scatter: re-read chunk, scatter to brec[j*BCAP + off[b][j] + LDS cursor]
//   5. k_passB:   per-bucket: fixed-point deg sums, LDS counting sort -> CSR, dis, row_ptr
//   6. k_norm:    val = dis[s]*w*dis[d] in place
// Then encoder MLP (32 nodes/block), 3x fused layer (SpMM gather + 64x64 dense
// + bias + relu), 1x layer+decoder fused.
// r8 experiment: nontemporal gather loads + nontemporal hout stores in the
// layer kernels (L1-bypass / L2-pollution hypothesis for the 2.45 TB/s rate).

constexpr int NN   = 100000;
constexpr int NE   = 1600000;
constexpr int INPD = 8;
constexpr int EMBD = 64;
constexpr float FPSCALE = 16777216.0f;   // 2^24
constexpr int LNODES = 32;               // nodes per k_layer block (512 threads)
constexpr int BNODES = 256;              // nodes per bucket
constexpr int NBUCK  = (NN + BNODES - 1) / BNODES;  // 391
constexpr int BCAP   = 5120;             // bucket capacity (avg 4096, ~16 sigma margin)
constexpr int NBLKA  = 512;              // blocks in hist/scatter
constexpr int CHUNKA = (NE + NBLKA - 1) / NBLKA;    // 3125

typedef float f32x4 __attribute__((ext_vector_type(4)));

// ---- CSR build ----
__global__ __launch_bounds__(512) void k_hist(const int* __restrict__ ei,
                                              int* __restrict__ hist) {
    __shared__ int lcnt[NBUCK];
    int tid = threadIdx.x;
    int beg = blockIdx.x * CHUNKA;
    int end = beg + CHUNKA; if (end > NE) end = NE;
    for (int i = tid; i < NBUCK; i += 512) lcnt[i] = 0;
    __syncthreads();
    for (int e = beg + tid; e < end; e += 512)
        atomicAdd(&lcnt[ei[NE + e] >> 8], 1);
    __syncthreads();
    for (int i = tid; i < NBUCK; i += 512) hist[blockIdx.x * NBUCK + i] = lcnt[i];
}

// one block per bucket j: exclusive scan of hist[0..511][j] in place; totals[j]
__global__ __launch_bounds__(512) void k_colscan(int* __restrict__ hist,
                                                 int* __restrict__ totals) {
    __shared__ int s[512];
    int j = blockIdx.x;
    int b = threadIdx.x;
    int v = hist[b * NBUCK + j];
    s[b] = v;
    __syncthreads();
    for (int off = 1; off < 512; off <<= 1) {
        int t = (b >= off) ? s[b - off] : 0;
        __syncthreads();
        s[b] += t;
        __syncthreads();
    }
    hist[b * NBUCK + j] = s[b] - v;          // exclusive prefix (within bucket)
    if (b == 511) totals[j] = s[b];
}

__global__ __launch_bounds__(512) void k_bscan(const int* __restrict__ totals,
                                               int* __restrict__ bucket_base,
                                               int* __restrict__ row_ptr) {
    __shared__ int s[512];
    int tid = threadIdx.x;
    int v = (tid < NBUCK) ? totals[tid] : 0;
    s[tid] = v;
    __syncthreads();
    for (int off = 1; off < 512; off <<= 1) {
        int t = (tid >= off) ? s[tid - off] : 0;
        __syncthreads();
        s[tid] += t;
        __syncthreads();
    }
    if (tid < NBUCK) bucket_base[tid + 1] = s[tid];
    if (tid == 0) { bucket_base[0] = 0; row_ptr[NN] = NE; }
}

// key = s | (d_local << 17)
__global__ __launch_bounds__(512) void k_scatter(const int* __restrict__ ei,
                                                 const float* __restrict__ w,
                                                 const int* __restrict__ hist,
                                                 int2* __restrict__ brec) {
    __shared__ int lbase[NBUCK];
    __shared__ int lcnt[NBUCK];
    int tid = threadIdx.x;
    int beg = blockIdx.x * CHUNKA;
    int end = beg + CHUNKA; if (end > NE) end = NE;
    for (int i = tid; i < NBUCK; i += 512) {
        lbase[i] = hist[blockIdx.x * NBUCK + i];
        lcnt[i] = 0;
    }
    __syncthreads();
    for (int e = beg + tid; e < end; e += 512) {
        int s = ei[e];
        int d = ei[NE + e];
        int b = d >> 8, dl = d & 255;
        int pos = lbase[b] + atomicAdd(&lcnt[b], 1);
        if (pos < BCAP)
            brec[(size_t)b * BCAP + pos] = make_int2(s | (dl << 17), __float_as_int(w[e]));
    }
}

__global__ __launch_bounds__(256) void k_passB(const int2* __restrict__ brec,
                                               const int* __restrict__ totals,
                                               const int* __restrict__ bucket_base,
                                               float* __restrict__ dis,
                                               int* __restrict__ row_ptr,
                                               int2* __restrict__ csr) {
    __shared__ int2 sbuf[BCAP];              // 40 KB
    __shared__ unsigned int sdeg[BNODES];
    __shared__ int scnt[BNODES];
    __shared__ int sincl[BNODES];
    __shared__ int scur[BNODES];
    int b = blockIdx.x;
    int tid = threadIdx.x;
    int n = totals[b]; if (n > BCAP) n = BCAP;
    int nodes = NN - b * BNODES; if (nodes > BNODES) nodes = BNODES;
    const int2* rec = brec + (size_t)b * BCAP;

    sdeg[tid] = 0; scnt[tid] = 0;
    __syncthreads();
    for (int i = tid; i < n; i += 256) {
        int2 r = rec[i];
        int dl = (r.x >> 17) & 255;
        unsigned int fx = (unsigned int)(__int_as_float(r.y) * FPSCALE + 0.5f);
        atomicAdd(&sdeg[dl], fx);
        atomicAdd(&scnt[dl], 1);
    }
    __syncthreads();
    sincl[tid] = scnt[tid];
    __syncthreads();
    for (int off = 1; off < 256; off <<= 1) {
        int t = (tid >= off) ? sincl[tid - off] : 0;
        __syncthreads();
        sincl[tid] += t;
        __syncthreads();
    }
    int excl = sincl[tid] - scnt[tid];
    scur[tid] = excl;
    int base = bucket_base[b];
    if (tid < nodes) {
        float deg = 1.0f + (float)sdeg[tid] * (1.0f / FPSCALE);  // + self loop
        dis[b * BNODES + tid] = 1.0f / sqrtf(deg);
        row_ptr[b * BNODES + tid] = base + excl;
    }
    __syncthreads();
    for (int i = tid; i < n; i += 256) {
        int2 r = rec[i];
        int dl = (r.x >> 17) & 255;
        int p = atomicAdd(&scur[dl], 1);
        sbuf[p] = r;
    }
    __syncthreads();
    for (int i = tid; i < n; i += 256) csr[base + i] = sbuf[i];
}

__global__ __launch_bounds__(256) void k_norm(const int* __restrict__ bucket_base,
                                              const float* __restrict__ dis,
                                              int2* __restrict__ csr) {
    int b = blockIdx.x;
    int tid = threadIdx.x;
    int base = bucket_base[b];
    int n = bucket_base[b + 1] - base;
    for (int i = tid; i < n; i += 256) {
        int2 r = csr[base + i];
        int s = r.x & 0x1FFFF;
        int dl = (r.x >> 17) & 255;
        float v = dis[s] * __int_as_float(r.y) * dis[b * BNODES + dl];
        csr[base + i] = make_int2(r.x, __float_as_int(v));
    }
}

// ---- dense ops ----
// encoder: h = relu(x@W1+b1)@W2 + b2 ; 32 nodes per 256-thread block
__global__ __launch_bounds__(256) void k_encoder(const float* __restrict__ x,
                                                 const float* __restrict__ w1,
                                                 const float* __restrict__ b1,
                                                 const float* __restrict__ w2,
                                                 const float* __restrict__ b2,
                                                 float* __restrict__ h) {
    __shared__ float sW1[INPD * EMBD];
    __shared__ float sW2[EMBD * EMBD];
    __shared__ float sB1[EMBD];
    __shared__ float sB2[EMBD];
    __shared__ float sZ[32][EMBD];
    int tid = threadIdx.x;
    for (int i = tid; i < INPD * EMBD; i += 256) sW1[i] = w1[i];
    for (int i = tid; i < EMBD * EMBD; i += 256) sW2[i] = w2[i];
    if (tid < EMBD) { sB1[tid] = b1[tid]; sB2[tid] = b2[tid]; }
    __syncthreads();
    int base = blockIdx.x * 32;
    #pragma unroll
    for (int it = 0; it < 8; ++it) {
        int item = tid + it * 256;
        int nl = item >> 6, j = item & 63;
        int node = base + nl;
        float acc = sB1[j];
        if (node < NN) {
            const float* xr = x + (size_t)node * INPD;
            #pragma unroll
            for (int k = 0; k < INPD; ++k) acc += xr[k] * sW1[k * EMBD + j];
        }
        sZ[nl][j] = fmaxf(acc, 0.0f);
    }
    __syncthreads();
    #pragma unroll
    for (int it = 0; it < 8; ++it) {
        int item = tid + it * 256;
        int nl = item >> 6, j2 = item & 63;
        int node = base + nl;
        if (node < NN) {
            float acc = sB2[j2];
            for (int j = 0; j < EMBD; ++j) acc += sZ[nl][j] * sW2[j * EMBD + j2];
            h[(size_t)node * EMBD + j2] = acc;
        }
    }
}

// fused layer: agg = dis[n]^2*h[n] + sum_e val[e]*h[col[e]] ; hout = relu(agg @ W + b)
// nontemporal gathers (no L1/L2 retention) + nontemporal output stores
__global__ __launch_bounds__(512) void k_layer(const float* __restrict__ hin,
                                               const float* __restrict__ dis,
                                               const int* __restrict__ row_ptr,
                                               const int2* __restrict__ edges,
                                               const float* __restrict__ W,
                                               const float* __restrict__ bias,
                                               float* __restrict__ hout) {
    __shared__ float sW[EMBD * EMBD];
    __shared__ float sB[EMBD];
    __shared__ float sA[LNODES][EMBD];
    int tid = threadIdx.x;
    for (int i = tid; i < EMBD * EMBD; i += 512) sW[i] = W[i];
    if (tid < EMBD) sB[tid] = bias[tid];

    int g = tid >> 4, l = tid & 15;
    int node = blockIdx.x * LNODES + g;
    const f32x4* h4 = (const f32x4*)hin;
    f32x4 a0 = (f32x4)(0.f), a1 = (f32x4)(0.f), a2 = (f32x4)(0.f), a3 = (f32x4)(0.f);
    if (node < NN) {
        float dsn = dis[node];
        float sn = dsn * dsn;
        a0 = sn * __builtin_nontemporal_load(h4 + (size_t)node * 16 + l);
        int beg = row_ptr[node], end = row_ptr[node + 1];
        int e = beg;
        for (; e + 4 <= end; e += 4) {
            int2 e0 = edges[e], e1 = edges[e + 1], e2 = edges[e + 2], e3 = edges[e + 3];
            f32x4 t0 = __builtin_nontemporal_load(h4 + (size_t)(e0.x & 0x1FFFF) * 16 + l);
            f32x4 t1 = __builtin_nontemporal_load(h4 + (size_t)(e1.x & 0x1FFFF) * 16 + l);
            f32x4 t2 = __builtin_nontemporal_load(h4 + (size_t)(e2.x & 0x1FFFF) * 16 + l);
            f32x4 t3 = __builtin_nontemporal_load(h4 + (size_t)(e3.x & 0x1FFFF) * 16 + l);
            a0 += __int_as_float(e0.y) * t0;
            a1 += __int_as_float(e1.y) * t1;
            a2 += __int_as_float(e2.y) * t2;
            a3 += __int_as_float(e3.y) * t3;
        }
        for (; e < end; ++e) {
            int2 ev = edges[e];
            f32x4 tv = __builtin_nontemporal_load(h4 + (size_t)(ev.x & 0x1FFFF) * 16 + l);
            a0 += __int_as_float(ev.y) * tv;
        }
    }
    a0 += a1 + a2 + a3;
    ((f32x4*)&sA[g][0])[l] = a0;
    __syncthreads();

    int base = blockIdx.x * LNODES;
    #pragma unroll
    for (int it = 0; it < 4; ++it) {
        int item = tid + it * 512;
        int nl = item >> 6, j2 = item & 63;
        int onode = base + nl;
        if (onode < NN) {
            float o = sB[j2];
            for (int k = 0; k < EMBD; ++k) o += sA[nl][k] * sW[k * EMBD + j2];
            __builtin_nontemporal_store(fmaxf(o, 0.0f), &hout[(size_t)onode * EMBD + j2]);
        }
    }
}

// layer 4 + decoder fused: h4 = relu(agg@W+b); z = relu(h4@W1d+b1d); out = z.w2d + b2d
__global__ __launch_bounds__(512) void k_layer_dec(const float* __restrict__ hin,
                                                   const float* __restrict__ dis,
                                                   const int* __restrict__ row_ptr,
                                                   const int2* __restrict__ edges,
                                                   const float* __restrict__ W,
                                                   const float* __restrict__ bias,
                                                   const float* __restrict__ w1d,
                                                   const float* __restrict__ b1d,
                                                   const float* __restrict__ w2d,
                                                   const float* __restrict__ b2d,
                                                   float* __restrict__ out) {
    __shared__ float sW[EMBD * EMBD];
    __shared__ float sW1d[EMBD * EMBD];
    __shared__ float sB[EMBD];
    __shared__ float sB1d[EMBD];
    __shared__ float sW2d[EMBD];
    __shared__ float sA[LNODES][EMBD];
    int tid = threadIdx.x;
    for (int i = tid; i < EMBD * EMBD; i += 512) { sW[i] = W[i]; sW1d[i] = w1d[i]; }
    if (tid < EMBD) { sB[tid] = bias[tid]; sB1d[tid] = b1d[tid]; sW2d[tid] = w2d[tid]; }

    int g = tid >> 4, l = tid & 15;
    int node = blockIdx.x * LNODES + g;
    const f32x4* h4 = (const f32x4*)hin;
    f32x4 a0 = (f32x4)(0.f), a1 = (f32x4)(0.f), a2 = (f32x4)(0.f), a3 = (f32x4)(0.f);
    if (node < NN) {
        float dsn = dis[node];
        float sn = dsn * dsn;
        a0 = sn * __builtin_nontemporal_load(h4 + (size_t)node * 16 + l);
        int beg = row_ptr[node], end = row_ptr[node + 1];
        int e = beg;
        for (; e + 4 <= end; e += 4) {
            int2 e0 = edges[e], e1 = edges[e + 1], e2 = edges[e + 2], e3 = edges[e + 3];
            f32x4 t0 = __builtin_nontemporal_load(h4 + (size_t)(e0.x & 0x1FFFF) * 16 + l);
            f32x4 t1 = __builtin_nontemporal_load(h4 + (size_t)(e1.x & 0x1FFFF) * 16 + l);
            f32x4 t2 = __builtin_nontemporal_load(h4 + (size_t)(e2.x & 0x1FFFF) * 16 + l);
            f32x4 t3 = __builtin_nontemporal_load(h4 + (size_t)(e3.x & 0x1FFFF) * 16 + l);
            a0 += __int_as_float(e0.y) * t0;
            a1 += __int_as_float(e1.y) * t1;
            a2 += __int_as_float(e2.y) * t2;
            a3 += __int_as_float(e3.y) * t3;
        }
        for (; e < end; ++e) {
            int2 ev = edges[e];
            f32x4 tv = __builtin_nontemporal_load(h4 + (size_t)(ev.x & 0x1FFFF) * 16 + l);
            a0 += __int_as_float(ev.y) * tv;
        }
    }
    a0 += a1 + a2 + a3;
    ((f32x4*)&sA[g][0])[l] = a0;
    __syncthreads();

    // h4-layer dense into registers, then back to sA
    float hv[4];
    #pragma unroll
    for (int it = 0; it < 4; ++it) {
        int item = tid + it * 512;
        int nl = item >> 6, j2 = item & 63;
        float o = sB[j2];
        for (int k = 0; k < EMBD; ++k) o += sA[nl][k] * sW[k * EMBD + j2];
        hv[it] = fmaxf(o, 0.0f);
    }
    __syncthreads();
    #pragma unroll
    for (int it = 0; it < 4; ++it) {
        int item = tid + it * 512;
        sA[item >> 6][item & 63] = hv[it];
    }
    __syncthreads();

    // decoder hidden dense into registers, then back to sA
    float zv[4];
    #pragma unroll
    for (int it = 0; it < 4; ++it) {
        int item = tid + it * 512;
        int nl = item >> 6, j2 = item & 63;
        float o = sB1d[j2];
        for (int k = 0; k < EMBD; ++k) o += sA[nl][k] * sW1d[k * EMBD + j2];
        zv[it] = fmaxf(o, 0.0f);
    }
    __syncthreads();
    #pragma unroll
    for (int it = 0; it < 4; ++it) {
        int item = tid + it * 512;
        sA[item >> 6][item & 63] = zv[it];
    }
    __syncthreads();

    // out[node] = dot(z, w2d) + b2d ; 16 lanes per node
    float r = 0.0f;
    #pragma unroll
    for (int u = 0; u < 4; ++u) r += sA[g][l * 4 + u] * sW2d[l * 4 + u];
    r += __shfl_xor(r, 1);
    r += __shfl_xor(r, 2);
    r += __shfl_xor(r, 4);
    r += __shfl_xor(r, 8);
    if (l == 0 && node < NN) out[node] = r + b2d[0];
}

extern "C" void kernel_launch(void* const* d_in, const int* in_sizes, int n_in,
                              void* d_out, int out_size, void* d_ws, size_t ws_size,
                              hipStream_t stream) {
    const float* x      = (const float*)d_in[0];
    const int*   ei     = (const int*)  d_in[1];
    const float* ew     = (const float*)d_in[2];
    const float* enc_w1 = (const float*)d_in[3];
    const float* enc_b1 = (const float*)d_in[4];
    const float* enc_w2 = (const float*)d_in[5];
    const float* enc_b2 = (const float*)d_in[6];
    const float* gcn_w  = (const float*)d_in[7];
    const float* gcn_b  = (const float*)d_in[8];
    const float* dec_w1 = (const float*)d_in[9];
    const float* dec_b1 = (const float*)d_in[10];
    const float* dec_w2 = (const float*)d_in[11];
    const float* dec_b2 = (const float*)d_in[12];
    float* out = (float*)d_out;

    char* ws = (char*)d_ws;
    size_t off = 0;
    auto alloc = [&](size_t bytes) -> void* {
        void* p = (void*)(ws + off);
        off += (bytes + 511) & ~(size_t)511;
        return p;
    };
    int*   hist        = (int*)  alloc((size_t)NBLKA * NBUCK * 4);  // 800 KB
    int*   totals      = (int*)  alloc(NBUCK * 4);
    int*   bucket_base = (int*)  alloc((NBUCK + 1) * 4);
    int2*  brec        = (int2*) alloc((size_t)NBUCK * BCAP * 8);   // 16 MB
    float* dis         = (float*)alloc(NN * 4);
    int*   row_ptr     = (int*)  alloc((NN + 1) * 4);
    int2*  csr         = (int2*) alloc((size_t)NE * 8);
    float* hbuf        = (float*)alloc((size_t)NN * EMBD * 4);
    float* hbuf2       = (float*)alloc((size_t)NN * EMBD * 4);
    (void)ws_size; (void)n_in; (void)in_sizes; (void)out_size;

    int gE32 = (NN + 31) / 32;
    int gL   = (NN + LNODES - 1) / LNODES;

    k_hist<<<NBLKA, 512, 0, stream>>>(ei, hist);
    k_colscan<<<NBUCK, 512, 0, stream>>>(hist, totals);
    k_bscan<<<1, 512, 0, stream>>>(totals, bucket_base, row_ptr);
    k_scatter<<<NBLKA, 512, 0, stream>>>(ei, ew, hist, brec);
    k_passB<<<NBUCK, 256, 0, stream>>>(brec, totals, bucket_base, dis, row_ptr, csr);
    k_norm<<<NBUCK, 256, 0, stream>>>(bucket_base, dis, csr);

    k_encoder<<<gE32, 256, 0, stream>>>(x, enc_w1, enc_b1, enc_w2, enc_b2, hbuf);

    float* cur = hbuf;
    float* nxt = hbuf2;
    for (int layer = 0; layer < 3; ++layer) {
        k_layer<<<gL, 512, 0, stream>>>(cur, dis, row_ptr, csr,
                                        gcn_w + (size_t)layer * EMBD * EMBD,
                                        gcn_b + (size_t)layer * EMBD, nxt);
        float* tmp = cur; cur = nxt; nxt = tmp;
    }
    k_layer_dec<<<gL, 512, 0, stream>>>(cur, dis, row_ptr, csr,
                                        gcn_w + (size_t)3 * EMBD * EMBD,
                                        gcn_b + (size_t)3 * EMBD,
                                        dec_w1, dec_b1, dec_w2, dec_b2, out);
}

// Round 9
// 437.810 us; speedup vs baseline: 1.1516x; 1.1516x over previous
//
#include <hip/hip_runtime.h>

// FillSimNet: 4-layer GCN forward.
// CSR build, atomic-free at global scope (deterministic 2-phase bucketing):
//   k_hist -> k_colscan -> k_bscan -> k_scatter -> k_passB -> k_norm
// Then encoder MLP, 3x fused layer, 1x layer+decoder fused.
// r9: reverted nontemporal (r8 regression: L2/L3 retention of h is load-bearing).
//     k_layer/k_layer_dec dense phase is wave-local: replaced block-wide
//     __syncthreads with in-wave s_waitcnt lgkmcnt(0)+sched_barrier (degree
//     variance: wave waits on max of 4 node degrees, not 32; waves overlap).
//     sA dense reads vectorized f32x4.

constexpr int NN   = 100000;
constexpr int NE   = 1600000;
constexpr int INPD = 8;
constexpr int EMBD = 64;
constexpr float FPSCALE = 16777216.0f;   // 2^24
constexpr int LNODES = 32;               // nodes per k_layer block (512 threads)
constexpr int BNODES = 256;              // nodes per bucket
constexpr int NBUCK  = (NN + BNODES - 1) / BNODES;  // 391
constexpr int BCAP   = 5120;             // bucket capacity (avg 4096, ~16 sigma margin)
constexpr int NBLKA  = 512;              // blocks in hist/scatter
constexpr int CHUNKA = (NE + NBLKA - 1) / NBLKA;    // 3125

typedef float f32x4 __attribute__((ext_vector_type(4)));

#define WAVE_LDS_FENCE() do { \
    asm volatile("s_waitcnt lgkmcnt(0)" ::: "memory"); \
    __builtin_amdgcn_sched_barrier(0); \
} while (0)

// ---- CSR build ----
__global__ __launch_bounds__(512) void k_hist(const int* __restrict__ ei,
                                              int* __restrict__ hist) {
    __shared__ int lcnt[NBUCK];
    int tid = threadIdx.x;
    int beg = blockIdx.x * CHUNKA;
    int end = beg + CHUNKA; if (end > NE) end = NE;
    for (int i = tid; i < NBUCK; i += 512) lcnt[i] = 0;
    __syncthreads();
    for (int e = beg + tid; e < end; e += 512)
        atomicAdd(&lcnt[ei[NE + e] >> 8], 1);
    __syncthreads();
    for (int i = tid; i < NBUCK; i += 512) hist[blockIdx.x * NBUCK + i] = lcnt[i];
}

// one block per bucket j: exclusive scan of hist[0..511][j] in place; totals[j]
__global__ __launch_bounds__(512) void k_colscan(int* __restrict__ hist,
                                                 int* __restrict__ totals) {
    __shared__ int s[512];
    int j = blockIdx.x;
    int b = threadIdx.x;
    int v = hist[b * NBUCK + j];
    s[b] = v;
    __syncthreads();
    for (int off = 1; off < 512; off <<= 1) {
        int t = (b >= off) ? s[b - off] : 0;
        __syncthreads();
        s[b] += t;
        __syncthreads();
    }
    hist[b * NBUCK + j] = s[b] - v;          // exclusive prefix (within bucket)
    if (b == 511) totals[j] = s[b];
}

__global__ __launch_bounds__(512) void k_bscan(const int* __restrict__ totals,
                                               int* __restrict__ bucket_base,
                                               int* __restrict__ row_ptr) {
    __shared__ int s[512];
    int tid = threadIdx.x;
    int v = (tid < NBUCK) ? totals[tid] : 0;
    s[tid] = v;
    __syncthreads();
    for (int off = 1; off < 512; off <<= 1) {
        int t = (tid >= off) ? s[tid - off] : 0;
        __syncthreads();
        s[tid] += t;
        __syncthreads();
    }
    if (tid < NBUCK) bucket_base[tid + 1] = s[tid];
    if (tid == 0) { bucket_base[0] = 0; row_ptr[NN] = NE; }
}

// key = s | (d_local << 17)
__global__ __launch_bounds__(512) void k_scatter(const int* __restrict__ ei,
                                                 const float* __restrict__ w,
                                                 const int* __restrict__ hist,
                                                 int2* __restrict__ brec) {
    __shared__ int lbase[NBUCK];
    __shared__ int lcnt[NBUCK];
    int tid = threadIdx.x;
    int beg = blockIdx.x * CHUNKA;
    int end = beg + CHUNKA; if (end > NE) end = NE;
    for (int i = tid; i < NBUCK; i += 512) {
        lbase[i] = hist[blockIdx.x * NBUCK + i];
        lcnt[i] = 0;
    }
    __syncthreads();
    for (int e = beg + tid; e < end; e += 512) {
        int s = ei[e];
        int d = ei[NE + e];
        int b = d >> 8, dl = d & 255;
        int pos = lbase[b] + atomicAdd(&lcnt[b], 1);
        if (pos < BCAP)
            brec[(size_t)b * BCAP + pos] = make_int2(s | (dl << 17), __float_as_int(w[e]));
    }
}

__global__ __launch_bounds__(256) void k_passB(const int2* __restrict__ brec,
                                               const int* __restrict__ totals,
                                               const int* __restrict__ bucket_base,
                                               float* __restrict__ dis,
                                               int* __restrict__ row_ptr,
                                               int2* __restrict__ csr) {
    __shared__ int2 sbuf[BCAP];              // 40 KB
    __shared__ unsigned int sdeg[BNODES];
    __shared__ int scnt[BNODES];
    __shared__ int sincl[BNODES];
    __shared__ int scur[BNODES];
    int b = blockIdx.x;
    int tid = threadIdx.x;
    int n = totals[b]; if (n > BCAP) n = BCAP;
    int nodes = NN - b * BNODES; if (nodes > BNODES) nodes = BNODES;
    const int2* rec = brec + (size_t)b * BCAP;

    sdeg[tid] = 0; scnt[tid] = 0;
    __syncthreads();
    for (int i = tid; i < n; i += 256) {
        int2 r = rec[i];
        int dl = (r.x >> 17) & 255;
        unsigned int fx = (unsigned int)(__int_as_float(r.y) * FPSCALE + 0.5f);
        atomicAdd(&sdeg[dl], fx);
        atomicAdd(&scnt[dl], 1);
    }
    __syncthreads();
    sincl[tid] = scnt[tid];
    __syncthreads();
    for (int off = 1; off < 256; off <<= 1) {
        int t = (tid >= off) ? sincl[tid - off] : 0;
        __syncthreads();
        sincl[tid] += t;
        __syncthreads();
    }
    int excl = sincl[tid] - scnt[tid];
    scur[tid] = excl;
    int base = bucket_base[b];
    if (tid < nodes) {
        float deg = 1.0f + (float)sdeg[tid] * (1.0f / FPSCALE);  // + self loop
        dis[b * BNODES + tid] = 1.0f / sqrtf(deg);
        row_ptr[b * BNODES + tid] = base + excl;
    }
    __syncthreads();
    for (int i = tid; i < n; i += 256) {
        int2 r = rec[i];
        int dl = (r.x >> 17) & 255;
        int p = atomicAdd(&scur[dl], 1);
        sbuf[p] = r;
    }
    __syncthreads();
    for (int i = tid; i < n; i += 256) csr[base + i] = sbuf[i];
}

__global__ __launch_bounds__(256) void k_norm(const int* __restrict__ bucket_base,
                                              const float* __restrict__ dis,
                                              int2* __restrict__ csr) {
    int b = blockIdx.x;
    int tid = threadIdx.x;
    int base = bucket_base[b];
    int n = bucket_base[b + 1] - base;
    for (int i = tid; i < n; i += 256) {
        int2 r = csr[base + i];
        int s = r.x & 0x1FFFF;
        int dl = (r.x >> 17) & 255;
        float v = dis[s] * __int_as_float(r.y) * dis[b * BNODES + dl];
        csr[base + i] = make_int2(r.x, __float_as_int(v));
    }
}

// ---- dense ops ----
// encoder: h = relu(x@W1+b1)@W2 + b2 ; 32 nodes per 256-thread block
__global__ __launch_bounds__(256) void k_encoder(const float* __restrict__ x,
                                                 const float* __restrict__ w1,
                                                 const float* __restrict__ b1,
                                                 const float* __restrict__ w2,
                                                 const float* __restrict__ b2,
                                                 float* __restrict__ h) {
    __shared__ float sW1[INPD * EMBD];
    __shared__ float sW2[EMBD * EMBD];
    __shared__ float sB1[EMBD];
    __shared__ float sB2[EMBD];
    __shared__ float sZ[32][EMBD];
    int tid = threadIdx.x;
    for (int i = tid; i < INPD * EMBD; i += 256) sW1[i] = w1[i];
    for (int i = tid; i < EMBD * EMBD; i += 256) sW2[i] = w2[i];
    if (tid < EMBD) { sB1[tid] = b1[tid]; sB2[tid] = b2[tid]; }
    __syncthreads();
    int base = blockIdx.x * 32;
    #pragma unroll
    for (int it = 0; it < 8; ++it) {
        int item = tid + it * 256;
        int nl = item >> 6, j = item & 63;
        int node = base + nl;
        float acc = sB1[j];
        if (node < NN) {
            const float* xr = x + (size_t)node * INPD;
            #pragma unroll
            for (int k = 0; k < INPD; ++k) acc += xr[k] * sW1[k * EMBD + j];
        }
        sZ[nl][j] = fmaxf(acc, 0.0f);
    }
    __syncthreads();
    #pragma unroll
    for (int it = 0; it < 8; ++it) {
        int item = tid + it * 256;
        int nl = item >> 6, j2 = item & 63;
        int node = base + nl;
        if (node < NN) {
            float acc = sB2[j2];
            for (int j = 0; j < EMBD; ++j) acc += sZ[nl][j] * sW2[j * EMBD + j2];
            h[(size_t)node * EMBD + j2] = acc;
        }
    }
}

// fused layer: agg = dis[n]^2*h[n] + sum_e val[e]*h[col[e]] ; hout = relu(agg @ W + b)
// 32 nodes / 512-thread block; wave-local dense (no mid-kernel barrier)
__global__ __launch_bounds__(512) void k_layer(const float* __restrict__ hin,
                                               const float* __restrict__ dis,
                                               const int* __restrict__ row_ptr,
                                               const int2* __restrict__ edges,
                                               const float* __restrict__ W,
                                               const float* __restrict__ bias,
                                               float* __restrict__ hout) {
    __shared__ float sW[EMBD * EMBD];
    __shared__ float sB[EMBD];
    __shared__ float sA[LNODES][EMBD];
    int tid = threadIdx.x;
    for (int i = tid; i < EMBD * EMBD; i += 512) sW[i] = W[i];
    if (tid < EMBD) sB[tid] = bias[tid];
    __syncthreads();   // weights staged; only barrier in the kernel

    int g = tid >> 4, l = tid & 15;
    int node = blockIdx.x * LNODES + g;
    const f32x4* h4 = (const f32x4*)hin;
    f32x4 a0 = (f32x4)(0.f), a1 = (f32x4)(0.f), a2 = (f32x4)(0.f), a3 = (f32x4)(0.f);
    if (node < NN) {
        float dsn = dis[node];
        float sn = dsn * dsn;
        a0 = sn * h4[(size_t)node * 16 + l];
        int beg = row_ptr[node], end = row_ptr[node + 1];
        int e = beg;
        for (; e + 4 <= end; e += 4) {
            int2 e0 = edges[e], e1 = edges[e + 1], e2 = edges[e + 2], e3 = edges[e + 3];
            f32x4 t0 = h4[(size_t)(e0.x & 0x1FFFF) * 16 + l];
            f32x4 t1 = h4[(size_t)(e1.x & 0x1FFFF) * 16 + l];
            f32x4 t2 = h4[(size_t)(e2.x & 0x1FFFF) * 16 + l];
            f32x4 t3 = h4[(size_t)(e3.x & 0x1FFFF) * 16 + l];
            a0 += __int_as_float(e0.y) * t0;
            a1 += __int_as_float(e1.y) * t1;
            a2 += __int_as_float(e2.y) * t2;
            a3 += __int_as_float(e3.y) * t3;
        }
        for (; e < end; ++e) {
            int2 ev = edges[e];
            f32x4 tv = h4[(size_t)(ev.x & 0x1FFFF) * 16 + l];
            a0 += __int_as_float(ev.y) * tv;
        }
    }
    a0 += a1 + a2 + a3;
    ((f32x4*)&sA[g][0])[l] = a0;
    WAVE_LDS_FENCE();   // wave-local: this wave wrote rows w*4..w*4+3, reads only those

    int w = tid >> 6, lane = tid & 63;
    int rbase = w * 4;
    int nbase = blockIdx.x * LNODES + rbase;
    #pragma unroll
    for (int r = 0; r < 4; ++r) {
        const f32x4* row = (const f32x4*)&sA[rbase + r][0];
        float o = sB[lane];
        #pragma unroll
        for (int kk = 0; kk < 16; ++kk) {
            f32x4 av = row[kk];
            o += av.x * sW[(kk * 4 + 0) * EMBD + lane];
            o += av.y * sW[(kk * 4 + 1) * EMBD + lane];
            o += av.z * sW[(kk * 4 + 2) * EMBD + lane];
            o += av.w * sW[(kk * 4 + 3) * EMBD + lane];
        }
        int onode = nbase + r;
        if (onode < NN) hout[(size_t)onode * EMBD + lane] = fmaxf(o, 0.0f);
    }
}

// layer 4 + decoder fused: h4 = relu(agg@W+b); z = relu(h4@W1d+b1d); out = z.w2d + b2d
// all stages wave-local
__global__ __launch_bounds__(512) void k_layer_dec(const float* __restrict__ hin,
                                                   const float* __restrict__ dis,
                                                   const int* __restrict__ row_ptr,
                                                   const int2* __restrict__ edges,
                                                   const float* __restrict__ W,
                                                   const float* __restrict__ bias,
                                                   const float* __restrict__ w1d,
                                                   const float* __restrict__ b1d,
                                                   const float* __restrict__ w2d,
                                                   const float* __restrict__ b2d,
                                                   float* __restrict__ out) {
    __shared__ float sW[EMBD * EMBD];
    __shared__ float sW1d[EMBD * EMBD];
    __shared__ float sB[EMBD];
    __shared__ float sB1d[EMBD];
    __shared__ float sW2d[EMBD];
    __shared__ float sA[LNODES][EMBD];
    int tid = threadIdx.x;
    for (int i = tid; i < EMBD * EMBD; i += 512) { sW[i] = W[i]; sW1d[i] = w1d[i]; }
    if (tid < EMBD) { sB[tid] = bias[tid]; sB1d[tid] = b1d[tid]; sW2d[tid] = w2d[tid]; }
    __syncthreads();

    int g = tid >> 4, l = tid & 15;
    int node = blockIdx.x * LNODES + g;
    const f32x4* h4 = (const f32x4*)hin;
    f32x4 a0 = (f32x4)(0.f), a1 = (f32x4)(0.f), a2 = (f32x4)(0.f), a3 = (f32x4)(0.f);
    if (node < NN) {
        float dsn = dis[node];
        float sn = dsn * dsn;
        a0 = sn * h4[(size_t)node * 16 + l];
        int beg = row_ptr[node], end = row_ptr[node + 1];
        int e = beg;
        for (; e + 4 <= end; e += 4) {
            int2 e0 = edges[e], e1 = edges[e + 1], e2 = edges[e + 2], e3 = edges[e + 3];
            f32x4 t0 = h4[(size_t)(e0.x & 0x1FFFF) * 16 + l];
            f32x4 t1 = h4[(size_t)(e1.x & 0x1FFFF) * 16 + l];
            f32x4 t2 = h4[(size_t)(e2.x & 0x1FFFF) * 16 + l];
            f32x4 t3 = h4[(size_t)(e3.x & 0x1FFFF) * 16 + l];
            a0 += __int_as_float(e0.y) * t0;
            a1 += __int_as_float(e1.y) * t1;
            a2 += __int_as_float(e2.y) * t2;
            a3 += __int_as_float(e3.y) * t3;
        }
        for (; e < end; ++e) {
            int2 ev = edges[e];
            f32x4 tv = h4[(size_t)(ev.x & 0x1FFFF) * 16 + l];
            a0 += __int_as_float(ev.y) * tv;
        }
    }
    a0 += a1 + a2 + a3;
    ((f32x4*)&sA[g][0])[l] = a0;
    WAVE_LDS_FENCE();

    int w = tid >> 6, lane = tid & 63;
    int rbase = w * 4;

    // layer-4 dense: hv = relu(agg @ W + b)
    float hv[4];
    #pragma unroll
    for (int r = 0; r < 4; ++r) {
        const f32x4* row = (const f32x4*)&sA[rbase + r][0];
        float o = sB[lane];
        #pragma unroll
        for (int kk = 0; kk < 16; ++kk) {
            f32x4 av = row[kk];
            o += av.x * sW[(kk * 4 + 0) * EMBD + lane];
            o += av.y * sW[(kk * 4 + 1) * EMBD + lane];
            o += av.z * sW[(kk * 4 + 2) * EMBD + lane];
            o += av.w * sW[(kk * 4 + 3) * EMBD + lane];
        }
        hv[r] = fmaxf(o, 0.0f);
    }
    WAVE_LDS_FENCE();   // all reads of sA done before overwrite
    #pragma unroll
    for (int r = 0; r < 4; ++r) sA[rbase + r][lane] = hv[r];
    WAVE_LDS_FENCE();

    // decoder hidden: zv = relu(hv @ W1d + b1d)
    float zv[4];
    #pragma unroll
    for (int r = 0; r < 4; ++r) {
        const f32x4* row = (const f32x4*)&sA[rbase + r][0];
        float o = sB1d[lane];
        #pragma unroll
        for (int kk = 0; kk < 16; ++kk) {
            f32x4 av = row[kk];
            o += av.x * sW1d[(kk * 4 + 0) * EMBD + lane];
            o += av.y * sW1d[(kk * 4 + 1) * EMBD + lane];
            o += av.z * sW1d[(kk * 4 + 2) * EMBD + lane];
            o += av.w * sW1d[(kk * 4 + 3) * EMBD + lane];
        }
        zv[r] = fmaxf(o, 0.0f);
    }
    WAVE_LDS_FENCE();
    #pragma unroll
    for (int r = 0; r < 4; ++r) sA[rbase + r][lane] = zv[r];
    WAVE_LDS_FENCE();

    // out[node] = dot(z, w2d) + b2d ; 16 lanes per node
    float r = 0.0f;
    #pragma unroll
    for (int u = 0; u < 4; ++u) r += sA[g][l * 4 + u] * sW2d[l * 4 + u];
    r += __shfl_xor(r, 1);
    r += __shfl_xor(r, 2);
    r += __shfl_xor(r, 4);
    r += __shfl_xor(r, 8);
    if (l == 0 && node < NN) out[node] = r + b2d[0];
}

extern "C" void kernel_launch(void* const* d_in, const int* in_sizes, int n_in,
                              void* d_out, int out_size, void* d_ws, size_t ws_size,
                              hipStream_t stream) {
    const float* x      = (const float*)d_in[0];
    const int*   ei     = (const int*)  d_in[1];
    const float* ew     = (const float*)d_in[2];
    const float* enc_w1 = (const float*)d_in[3];
    const float* enc_b1 = (const float*)d_in[4];
    const float* enc_w2 = (const float*)d_in[5];
    const float* enc_b2 = (const float*)d_in[6];
    const float* gcn_w  = (const float*)d_in[7];
    const float* gcn_b  = (const float*)d_in[8];
    const float* dec_w1 = (const float*)d_in[9];
    const float* dec_b1 = (const float*)d_in[10];
    const float* dec_w2 = (const float*)d_in[11];
    const float* dec_b2 = (const float*)d_in[12];
    float* out = (float*)d_out;

    char* ws = (char*)d_ws;
    size_t off = 0;
    auto alloc = [&](size_t bytes) -> void* {
        void* p = (void*)(ws + off);
        off += (bytes + 511) & ~(size_t)511;
        return p;
    };
    int*   hist        = (int*)  alloc((size_t)NBLKA * NBUCK * 4);  // 800 KB
    int*   totals      = (int*)  alloc(NBUCK * 4);
    int*   bucket_base = (int*)  alloc((NBUCK + 1) * 4);
    int2*  brec        = (int2*) alloc((size_t)NBUCK * BCAP * 8);   // 16 MB
    float* dis         = (float*)alloc(NN * 4);
    int*   row_ptr     = (int*)  alloc((NN + 1) * 4);
    int2*  csr         = (int2*) alloc((size_t)NE * 8);
    float* hbuf        = (float*)alloc((size_t)NN * EMBD * 4);
    float* hbuf2       = (float*)alloc((size_t)NN * EMBD * 4);
    (void)ws_size; (void)n_in; (void)in_sizes; (void)out_size;

    int gE32 = (NN + 31) / 32;
    int gL   = (NN + LNODES - 1) / LNODES;

    k_hist<<<NBLKA, 512, 0, stream>>>(ei, hist);
    k_colscan<<<NBUCK, 512, 0, stream>>>(hist, totals);
    k_bscan<<<1, 512, 0, stream>>>(totals, bucket_base, row_ptr);
    k_scatter<<<NBLKA, 512, 0, stream>>>(ei, ew, hist, brec);
    k_passB<<<NBUCK, 256, 0, stream>>>(brec, totals, bucket_base, dis, row_ptr, csr);
    k_norm<<<NBUCK, 256, 0, stream>>>(bucket_base, dis, csr);

    k_encoder<<<gE32, 256, 0, stream>>>(x, enc_w1, enc_b1, enc_w2, enc_b2, hbuf);

    float* cur = hbuf;
    float* nxt = hbuf2;
    for (int layer = 0; layer < 3; ++layer) {
        k_layer<<<gL, 512, 0, stream>>>(cur, dis, row_ptr, csr,
                                        gcn_w + (size_t)layer * EMBD * EMBD,
                                        gcn_b + (size_t)layer * EMBD, nxt);
        float* tmp = cur; cur = nxt; nxt = tmp;
    }
    k_layer_dec<<<gL, 512, 0, stream>>>(cur, dis, row_ptr, csr,
                                        gcn_w + (size_t)3 * EMBD * EMBD,
                                        gcn_b + (size_t)3 * EMBD,
                                        dec_w1, dec_b1, dec_w2, dec_b2, out);
}